// Round 17
// baseline (1128.536 us; speedup 1.0000x reference)
//
#include <hip/hip_runtime.h>
#include <cstdint>
#include <cstddef>

#define BB   16
#define NN   4096
#define CINN 64
#define KKK  64
#define HIDD 128
#define SSS  1024
#define MAXC 320
#define NCH  2
#define CHS  512       // FPS steps / centers per half-chunk
#define FPSB 51264     // per-cloud FPS LDS slice: 48KB pts + 64B slots + 2KB sel

typedef __attribute__((ext_vector_type(8))) short short8;
typedef __attribute__((ext_vector_type(4))) float f32x4;
typedef unsigned long long u64;

// Exact f32 squared distance, numpy-style: ((dx*dx + dy*dy) + dz*dz), no FMA contraction.
// MUST stay bit-identical (absmax 0.0 in round 1 proved selection equivalence).
__device__ __forceinline__ float d2_exact(float ax, float ay, float az,
                                          float bx, float by, float bz) {
  float dx = __fsub_rn(ax, bx);
  float dy = __fsub_rn(ay, by);
  float dz = __fsub_rn(az, bz);
  return __fadd_rn(__fadd_rn(__fmul_rn(dx, dx), __fmul_rn(dy, dy)), __fmul_rn(dz, dz));
}

// f32 -> bf16 round-to-nearest-even (no NaN inputs here)
__device__ __forceinline__ unsigned short f2bf(float f) {
  unsigned u = __float_as_uint(f);
  return (unsigned short)((u + 0x7fffu + ((u >> 16) & 1u)) >> 16);
}

// ---------------- FPS role: one 256-thread HALF-block per cloud (2 clouds share a block
// so each SIMD interleaves two independent serial chains). Body identical to round-13/16. ----------------
__device__ __forceinline__ void fps_role(int chunk, int cloud, int tid,
                                         const float* __restrict__ pos,
                                         int* __restrict__ fps_idx,
                                         float* __restrict__ md_ws,
                                         int* __restrict__ last_ws,
                                         float* __restrict__ pos_out,
                                         float* __restrict__ batch_out,
                                         char* smem) {
  __builtin_amdgcn_s_setprio(3);  // protect the serial critical path from co-resident waves
  float* px = (float*)smem;
  float* py = px + NN;
  float* pz = py + NN;
  u64* slots = (u64*)(pz + NN);      // [2][4] parity-double-buffered wave leaders (64B)
  int* sel = (int*)(slots + 8);      // [CHS] selected indices of this chunk
  const float* pb = pos + (size_t)cloud * NN * 3;
  for (int i = tid; i < NN; i += 256) {
    px[i] = pb[3 * i + 0];
    py[i] = pb[3 * i + 1];
    pz[i] = pb[3 * i + 2];
  }
  if (chunk == 0) {
    #pragma unroll
    for (int kk = 0; kk < 4; ++kk)
      batch_out[cloud * SSS + kk * 256 + tid] = (float)cloud;
  }
  __syncthreads();

  float qx[16], qy[16], qz[16], md[16];
  #pragma unroll
  for (int j = 0; j < 16; ++j) {
    const int i = j * 256 + tid;
    qx[j] = px[i]; qy[j] = py[i]; qz[j] = pz[i];
    asm volatile("" : "+v"(qx[j]), "+v"(qy[j]), "+v"(qz[j]));
    md[j] = __builtin_inff();
  }
  int last, tb;
  const int cbase = chunk * CHS;
  const int te = cbase + CHS;
  if (chunk == 0) {
    last = 0; tb = 1;
    if (tid == 0) {
      fps_idx[cloud * SSS] = 0;
      pos_out[(size_t)cloud * SSS * 3 + 0] = px[0];
      pos_out[(size_t)cloud * SSS * 3 + 1] = py[0];
      pos_out[(size_t)cloud * SSS * 3 + 2] = pz[0];
    }
  } else {
    #pragma unroll
    for (int j = 0; j < 16; ++j) md[j] = md_ws[cloud * 4096 + j * 256 + tid];
    last = last_ws[cloud]; tb = cbase;
  }

  for (int t = tb; t < te; ++t) {
    const float lx = px[last], ly = py[last], lz = pz[last];  // LDS broadcast
    float bv = -1.f;
    int bj = 0;
    #pragma unroll
    for (int j = 0; j < 16; ++j) {
      const float d = d2_exact(qx[j], qy[j], qz[j], lx, ly, lz);
      md[j] = fminf(md[j], d);
      if (md[j] > bv) { bv = md[j]; bj = j; }  // strict > : lowest j among ties
    }
    // key = (valbits<<32) | ~idx : u64 max == (max val, lowest idx) == jnp.argmax
    unsigned klo = ~(unsigned)(bj * 256 + tid);
    unsigned khi = __float_as_uint(bv);
    // DPP wavefront max-reduce to lane 63 (round-7 proven).
#define FPS_DPP_STAGE(CTRL, RMASK)                                                            \
    {                                                                                          \
      unsigned slo = (unsigned)__builtin_amdgcn_update_dpp(0, (int)klo, CTRL, RMASK, 0xf, true); \
      unsigned shi = (unsigned)__builtin_amdgcn_update_dpp(0, (int)khi, CTRL, RMASK, 0xf, true); \
      if ((((u64)shi << 32) | slo) > (((u64)khi << 32) | klo)) { khi = shi; klo = slo; }       \
    }
    FPS_DPP_STAGE(0x111, 0xf)  // row_shr:1
    FPS_DPP_STAGE(0x112, 0xf)  // row_shr:2
    FPS_DPP_STAGE(0x114, 0xf)  // row_shr:4
    FPS_DPP_STAGE(0x118, 0xf)  // row_shr:8
    FPS_DPP_STAGE(0x142, 0xa)  // row_bcast:15
    FPS_DPP_STAGE(0x143, 0xc)  // row_bcast:31 -> lane63 = wave max
#undef FPS_DPP_STAGE
    u64* sl = slots + (t & 1) * 4;
    if ((tid & 63) == 63) sl[tid >> 6] = ((u64)khi << 32) | klo;
    __syncthreads();  // block-wide; both halves hit identical barrier counts
    u64 mm = sl[0];
    #pragma unroll
    for (int w = 1; w < 4; ++w) mm = sl[w] > mm ? sl[w] : mm;
    last = (int)(~(unsigned)(mm & 0xffffffffull));
    if (tid == 0) sel[t - cbase] = last;   // buffer selection in LDS
  }

  // flush fps_idx + pos_out for this chunk (coalesced, off the critical path)
  __syncthreads();
  for (int e = tid; e < CHS; e += 256) {
    const int t2 = cbase + e;
    if (t2 == 0) continue;  // written at init
    const int idx = sel[e];
    fps_idx[cloud * SSS + t2] = idx;
    pos_out[((size_t)cloud * SSS + t2) * 3 + 0] = px[idx];
    pos_out[((size_t)cloud * SSS + t2) * 3 + 1] = py[idx];
    pos_out[((size_t)cloud * SSS + t2) * 3 + 2] = pz[idx];
  }
  if (chunk == 0) {
    #pragma unroll
    for (int j = 0; j < 16; ++j) md_ws[cloud * 4096 + j * 256 + tid] = md[j];
    if (tid == 0) last_ws[cloud] = last;
  }
}

// ---------------- y1 role: 512 thr, 32 points/block, XCD-affine; bit-identical per-element fma chain ----------------
__device__ __forceinline__ void y1_role(int j, int tid,
                                        const float* __restrict__ x,
                                        const float* __restrict__ W1,
                                        unsigned short* __restrict__ y1,
                                        char* smem) {
  float* sW = (float*)smem;             // [64][128] 32KB
  float* sx = (float*)(smem + 32768);   // [32][64] 8KB
  const int cloud = ((j >> 10) << 3) | (j & 7);  // 128 blocks/cloud, XCD-affine
  const int local = (j >> 3) & 127;
  const int p0 = cloud * NN + local * 32;
  for (int e = tid; e < CINN * HIDD; e += 512) sW[e] = W1[e];
  for (int e = tid; e < 32 * CINN; e += 512) sx[e] = x[(size_t)p0 * CINN + e];
  __syncthreads();
  const int h = tid & 127;
  const int pg = (tid >> 7) * 8;   // 4 groups x 8 points
  float a[8];
  #pragma unroll
  for (int k = 0; k < 8; ++k) a[k] = 0.f;
  for (int c = 0; c < CINN; ++c) {
    const float w = sW[c * HIDD + h];
    #pragma unroll
    for (int k = 0; k < 8; ++k) a[k] = fmaf(sx[(pg + k) * CINN + c], w, a[k]);
  }
  #pragma unroll
  for (int k = 0; k < 8; ++k)
    y1[(size_t)(p0 + pg + k) * HIDD + h] = f2bf(a[k]);
}

// ---------------- bq role: 8 centers/block, NT-templated strides (selection order-free) ----------------
template <int NT>
__device__ __forceinline__ void bq_role(int cc, int i, int tid,
                                        const float* __restrict__ pos,
                                        const int* __restrict__ fps_idx,
                                        int* __restrict__ nbr,
                                        int* __restrict__ cnt,
                                        char* smem) {
  const int b = i >> 6;                        // 64 blocks per cloud per half (CHS=512)
  const int t0 = cc * CHS + (i & 63) * 8;      // 8 consecutive centers
  const int gbase = b * SSS + t0;
  float* cd = (float*)smem;                    // [8][MAXC] d2, 10240B
  int*   ci = (int*)(smem + 10240);            // [8][MAXC] idx
  int*   ctr = (int*)(smem + 20480);           // [8]
  int*   scn = ctr + 8;                        // [8]
  float* cctr = (float*)(scn + 8);             // [8][3]

  const float* pb = pos + (size_t)b * NN * 3;
  if (tid < 8) { ctr[tid] = 0; scn[tid] = 0; }
  if (tid < 8) {
    const int cp = fps_idx[gbase + tid];
    cctr[tid * 3 + 0] = pb[cp * 3 + 0];
    cctr[tid * 3 + 1] = pb[cp * 3 + 1];
    cctr[tid * 3 + 2] = pb[cp * 3 + 2];
  }
  __syncthreads();
  float cx[8], cy[8], cz[8];
  #pragma unroll
  for (int c = 0; c < 8; ++c) {
    cx[c] = cctr[c * 3 + 0]; cy[c] = cctr[c * 3 + 1]; cz[c] = cctr[c * 3 + 2];
  }
  // scan straight from global (same bits as any staged copy => bit-identical selection)
  #pragma unroll 4
  for (int p = tid; p < NN; p += NT) {
    const float x = pb[3 * p + 0], y = pb[3 * p + 1], z = pb[3 * p + 2];
    #pragma unroll
    for (int c = 0; c < 8; ++c) {
      const float d2 = d2_exact(x, y, z, cx[c], cy[c], cz[c]);
      if (d2 <= 0.04f) {
        const int slot = atomicAdd(&ctr[c], 1);
        if (slot < MAXC) { cd[c * MAXC + slot] = d2; ci[c * MAXC + slot] = p; }
      }
    }
  }
  __syncthreads();
  // exact lex-rank (d2, idx) top-K == lax.top_k tie-break; order-independent
  #pragma unroll 1
  for (int c = 0; c < 8; ++c) {
    const int C = min(ctr[c], MAXC);
    for (int j = tid; j < C; j += NT) {
      const float dj = cd[c * MAXC + j];
      const int ij = ci[c * MAXC + j];
      int rank = 0;
      for (int m = 0; m < C; ++m) {
        const float dm = cd[c * MAXC + m];
        const int im = ci[c * MAXC + m];
        rank += (dm < dj || (dm == dj && im < ij)) ? 1 : 0;
      }
      if (rank < KKK) nbr[(size_t)(gbase + c) * KKK + atomicAdd(&scn[c], 1)] = ij;
    }
  }
  __syncthreads();
  if (tid < 8) cnt[gbase + tid] = scn[tid];
}

// ---------------- mlp role: round-16 proven low-VGPR version (unchanged) ----------------
__device__ __forceinline__ void mlp_role(int cc, int m, int tid,
                                         const float* __restrict__ pos,
                                         const unsigned short* __restrict__ y1,
                                         const float* __restrict__ W1,
                                         const float* __restrict__ b1,
                                         const unsigned short* __restrict__ W2t,
                                         const float* __restrict__ b2,
                                         const int* __restrict__ fps_idx,
                                         const int* __restrict__ nbr,
                                         const int* __restrict__ cnt,
                                         float* __restrict__ out,
                                         char* smem) {
  // m in [0,4096): XCD-affine cloud map; 256 pairs per cloud per half (CHS=512)
  const int b = ((m >> 11) << 3) | (m & 7);
  const int loc = (m >> 3) & 255;
  const int g0 = b * SSS + cc * CHS + loc * 2;
  char* Hb = smem;                        // h1 bf16 swizzled, 32KB
  float* s_ctr = (float*)(smem + 32768);  // [2][3]
  int* s_M = (int*)(smem + 32800);        // [2]
  int* s_pidx = (int*)(smem + 32832);     // [128]
  float* s_rel = (float*)(smem + 33344);  // [128][3]

  const int wv = tid >> 6, ln = tid & 63;
  const int mw = wv >> 1, nw = wv & 1;
  const int lr = ln & 15, lg = ln >> 4;

  if (tid < 2) {
    s_M[tid] = min(cnt[g0 + tid], KKK);
    const int cp = fps_idx[g0 + tid];
    s_ctr[tid * 3 + 0] = pos[((size_t)b * NN + cp) * 3 + 0];
    s_ctr[tid * 3 + 1] = pos[((size_t)b * NN + cp) * 3 + 1];
    s_ctr[tid * 3 + 2] = pos[((size_t)b * NN + cp) * 3 + 2];
  }
  __syncthreads();

  // cooperative precompute: row t -> neighbor index + rel (kills the per-row nbr->pos chain)
  if (tid < 128) {
    const int ci = tid >> 6, k = tid & 63;
    int p = -1;
    float rx = 0.f, ry = 0.f, rz = 0.f;
    if (k < s_M[ci]) {
      p = nbr[(size_t)(g0 + ci) * KKK + k];
      rx = pos[((size_t)b * NN + p) * 3 + 0] - s_ctr[ci * 3 + 0];
      ry = pos[((size_t)b * NN + p) * 3 + 1] - s_ctr[ci * 3 + 1];
      rz = pos[((size_t)b * NN + p) * 3 + 2] - s_ctr[ci * 3 + 2];
    }
    s_pidx[tid] = p;
    s_rel[tid * 3 + 0] = rx; s_rel[tid * 3 + 1] = ry; s_rel[tid * 3 + 2] = rz;
  }
  __syncthreads();

  const float2 b1v = *(const float2*)(b1 + ln * 2);
  const float2 wav = *(const float2*)(W1 + 64 * HIDD + ln * 2);
  const float2 wbv = *(const float2*)(W1 + 65 * HIDD + ln * 2);
  const float2 wcv = *(const float2*)(W1 + 66 * HIDD + ln * 2);
  const int rbase = wv * 32;
  // four register batches of 8: loads issue before consumers, low live-register count
  #pragma unroll
  for (int qb = 0; qb < 4; ++qb) {
    unsigned yreg[8];
    #pragma unroll
    for (int rr = 0; rr < 8; ++rr) {
      const int p = s_pidx[rbase + qb * 8 + rr];
      const int pa = p < 0 ? 0 : p;
      yreg[rr] = *(const unsigned*)(y1 + ((size_t)(b * NN + pa)) * HIDD + ln * 2);
    }
    #pragma unroll
    for (int rr = 0; rr < 8; ++rr) {
      const int r = rbase + qb * 8 + rr;
      const int p = s_pidx[r];
      unsigned val = 0u;
      if (p >= 0) {
        const float rx = s_rel[r * 3 + 0], ry = s_rel[r * 3 + 1], rz = s_rel[r * 3 + 2];
        const float y0 = __uint_as_float(yreg[rr] << 16);          // bf2f(low half)
        const float y1f = __uint_as_float(yreg[rr] & 0xffff0000u); // bf2f(high half)
        const float v0 = fmaxf(y0 + b1v.x + rx * wav.x + ry * wbv.x + rz * wcv.x, 0.f);
        const float v1 = fmaxf(y1f + b1v.y + rx * wav.y + ry * wbv.y + rz * wcv.y, 0.f);
        val = (unsigned)f2bf(v0) | ((unsigned)f2bf(v1) << 16);
      }
      *(unsigned*)(Hb + r * 256 + ((ln * 4) ^ ((r & 7) << 4))) = val;
    }
  }
  __syncthreads();

  // MFMA: wave (mw=center, nw=col-half); 4x4 16x16 tiles; K=128 in 4 steps of 32.
  // B-fragments loaded per-ks from global W2t (L2-broadcast) to keep live VGPRs low.
  f32x4 zero = {0.f, 0.f, 0.f, 0.f};
  f32x4 acc[4][4];
  #pragma unroll
  for (int mi = 0; mi < 4; ++mi)
    #pragma unroll
    for (int ni = 0; ni < 4; ++ni) acc[mi][ni] = zero;

  #pragma unroll
  for (int ks = 0; ks < 4; ++ks) {
    short8 bfr[4];
    #pragma unroll
    for (int ni = 0; ni < 4; ++ni)
      bfr[ni] = *(const short8*)(W2t + (size_t)(nw * 64 + ni * 16 + lr) * HIDD + ks * 32 + lg * 8);
    short8 af[4];
    #pragma unroll
    for (int mi = 0; mi < 4; ++mi) {
      const int row = mw * 64 + mi * 16 + lr;
      af[mi] = *(const short8*)(Hb + row * 256 + ((ks * 64 + lg * 16) ^ ((row & 7) << 4)));
    }
    #pragma unroll
    for (int mi = 0; mi < 4; ++mi)
      #pragma unroll
      for (int ni = 0; ni < 4; ++ni)
        acc[mi][ni] = __builtin_amdgcn_mfma_f32_16x16x32_bf16(af[mi], bfr[ni], acc[mi][ni], 0, 0, 0);
  }

  // epilogue: relu(acc+b2), mask k>=M to 0 (relu>=0, k=0 valid => exact), max over k
  const int cId = g0 + mw;
  const int Mc = s_M[mw];
  #pragma unroll
  for (int ni = 0; ni < 4; ++ni) {
    const float b2v = b2[nw * 64 + ni * 16 + lr];
    float cm = 0.f;
    #pragma unroll
    for (int mi = 0; mi < 4; ++mi)
      #pragma unroll
      for (int rr = 0; rr < 4; ++rr) {
        const int k = mi * 16 + lg * 4 + rr;   // C layout: col=lane&15, row=(lane>>4)*4+reg
        const float v = fmaxf(acc[mi][ni][rr] + b2v, 0.f);
        cm = fmaxf(cm, k < Mc ? v : 0.f);
      }
    cm = fmaxf(cm, __shfl_xor(cm, 16, 64));
    cm = fmaxf(cm, __shfl_xor(cm, 32, 64));
    if (ln < 16) out[(size_t)cId * HIDD + nw * 64 + ni * 16 + lr] = cm;
  }
}

// ============ P0: 8 dual-cloud FPS blocks || y1 (2048) || W2t — 512 threads ============
__global__ __launch_bounds__(512) void k_phase0(const float* __restrict__ x,
                                                const float* __restrict__ pos,
                                                const float* __restrict__ W1,
                                                const float* __restrict__ W2,
                                                unsigned short* __restrict__ W2t,
                                                int* __restrict__ fps_idx,
                                                unsigned short* __restrict__ y1,
                                                float* __restrict__ md_ws,
                                                int* __restrict__ last_ws,
                                                float* __restrict__ pos_out,
                                                float* __restrict__ batch_out) {
  __shared__ __align__(16) char smem[2 * FPSB];
  const int bid = blockIdx.x, tid = threadIdx.x;
  if (bid < 8) {
    const int half = tid >> 8, lt = tid & 255;
    fps_role(0, bid * 2 + half, lt, pos, fps_idx, md_ws, last_ws, pos_out, batch_out,
             smem + half * FPSB);
  } else if (bid < 8 + 2048) {
    y1_role(bid - 8, tid, x, W1, y1, smem);
  } else {
    for (int e = tid; e < HIDD * HIDD; e += 512) {
      const int n = e >> 7, hh = e & 127;
      W2t[e] = f2bf(W2[hh * HIDD + n]);   // W2t[n][h]
    }
  }
}

// ============ P1: 8 dual-cloud FPS blocks || bq0 (1024) — 512 threads ============
__global__ __launch_bounds__(512) void k_phase1(const float* __restrict__ pos,
                                                int* __restrict__ fps_idx,
                                                int* __restrict__ cnt,
                                                int* __restrict__ nbr,
                                                float* __restrict__ md_ws,
                                                int* __restrict__ last_ws,
                                                float* __restrict__ pos_out,
                                                float* __restrict__ batch_out) {
  __shared__ __align__(16) char smem[2 * FPSB];
  const int bid = blockIdx.x, tid = threadIdx.x;
  if (bid < 8) {
    const int half = tid >> 8, lt = tid & 255;
    fps_role(1, bid * 2 + half, lt, pos, fps_idx, md_ws, last_ws, pos_out, batch_out,
             smem + half * FPSB);
  } else {
    bq_role<512>(0, bid - 8, tid, pos, fps_idx, nbr, cnt, smem);
  }
}

__global__ __launch_bounds__(256) void k_phase2(const float* __restrict__ pos,
                                                const int* __restrict__ fps_idx,
                                                int* __restrict__ nbr,
                                                int* __restrict__ cnt) {
  __shared__ __align__(16) char smem[20736];   // 7 blocks/CU
  bq_role<256>(1, blockIdx.x, threadIdx.x, pos, fps_idx, nbr, cnt, smem);
}

__global__ __launch_bounds__(256) void k_phase3(const float* __restrict__ pos,
                                                const unsigned short* __restrict__ y1,
                                                const float* __restrict__ W1,
                                                const float* __restrict__ b1,
                                                const unsigned short* __restrict__ W2t,
                                                const float* __restrict__ b2,
                                                const int* __restrict__ fps_idx,
                                                const int* __restrict__ nbr,
                                                const int* __restrict__ cnt,
                                                float* __restrict__ out) {
  __shared__ __align__(16) char smem[34944];
  const int bid = blockIdx.x;
  mlp_role(bid >> 12, bid & 4095, threadIdx.x, pos, y1, W1, b1, W2t, b2,
           fps_idx, nbr, cnt, out, smem);
}

extern "C" void kernel_launch(void* const* d_in, const int* in_sizes, int n_in,
                              void* d_out, int out_size, void* d_ws, size_t ws_size,
                              hipStream_t stream) {
  const float* x   = (const float*)d_in[0];
  const float* pos = (const float*)d_in[1];
  const float* W1  = (const float*)d_in[3];
  const float* b1  = (const float*)d_in[4];
  const float* W2  = (const float*)d_in[5];
  const float* b2  = (const float*)d_in[6];

  float* out       = (float*)d_out;                   // [B*S, HID]
  float* pos_out   = out + (size_t)BB * SSS * HIDD;   // [B*S, 3]
  float* batch_out = pos_out + (size_t)BB * SSS * 3;  // [B*S]

  int* fps_idx        = (int*)d_ws;                                          // 64 KB
  int* cnt            = (int*)((char*)d_ws + 65536);                         // 64 KB
  unsigned short* W2t = (unsigned short*)((char*)d_ws + 131072);             // 32 KB
  int* last_ws        = (int*)((char*)d_ws + 163840);                        // 64 B
  int* nbr            = (int*)((char*)d_ws + 262144);                        // 4 MB
  unsigned short* y1  = (unsigned short*)((char*)d_ws + 262144 + 4194304);   // 16 MB (bf16)
  float* md_ws        = (float*)((char*)d_ws + 262144 + 4194304 + 33554432); // 256 KB

  k_phase0<<<8 + 2048 + 1, 512, 0, stream>>>(x, pos, W1, W2, W2t, fps_idx, y1,
                                             md_ws, last_ws, pos_out, batch_out);
  k_phase1<<<8 + 1024, 512, 0, stream>>>(pos, fps_idx, cnt, nbr,
                                         md_ws, last_ws, pos_out, batch_out);
  k_phase2<<<1024, 256, 0, stream>>>(pos, fps_idx, nbr, cnt);
  k_phase3<<<8192, 256, 0, stream>>>(pos, y1, W1, b1, W2t, b2,
                                     fps_idx, nbr, cnt, out);
}

// Round 18
// 1091.686 us; speedup vs baseline: 1.0338x; 1.0338x over previous
//
#include <hip/hip_runtime.h>
#include <cstdint>
#include <cstddef>

#define BB   16
#define NN   4096
#define CINN 64
#define KKK  64
#define HIDD 128
#define SSS  1024
#define MAXC 320
#define NCH  2
#define CHS  512   // FPS steps / centers per half-chunk

typedef __attribute__((ext_vector_type(8))) short short8;
typedef __attribute__((ext_vector_type(4))) float f32x4;
typedef unsigned long long u64;

// Exact f32 squared distance, numpy-style: ((dx*dx + dy*dy) + dz*dz), no FMA contraction.
// MUST stay bit-identical (absmax 0.0 in round 1 proved selection equivalence).
__device__ __forceinline__ float d2_exact(float ax, float ay, float az,
                                          float bx, float by, float bz) {
  float dx = __fsub_rn(ax, bx);
  float dy = __fsub_rn(ay, by);
  float dz = __fsub_rn(az, bz);
  return __fadd_rn(__fadd_rn(__fmul_rn(dx, dx), __fmul_rn(dy, dy)), __fmul_rn(dz, dz));
}

// f32 -> bf16 round-to-nearest-even (no NaN inputs here)
__device__ __forceinline__ unsigned short f2bf(float f) {
  unsigned u = __float_as_uint(f);
  return (unsigned short)((u + 0x7fffu + ((u >> 16) & 1u)) >> 16);
}

// ---------------- FPS role: coords carried in wave slots (no px[last] gather);
// tree+mask argmax (lowest-j tie-break == serial strict-> chain). Single cloud/block. ----------------
__device__ __forceinline__ void fps_role(int chunk, int bid, int tid,
                                         const float* __restrict__ pos,
                                         int* __restrict__ fps_idx,
                                         float* __restrict__ md_ws,
                                         int* __restrict__ last_ws,
                                         float* __restrict__ pos_out,
                                         float* __restrict__ batch_out,
                                         char* smem) {
  __builtin_amdgcn_s_setprio(3);
  float* px = (float*)smem;
  float* py = px + NN;
  float* pz = py + NN;
  u64* skey = (u64*)(pz + NN);          // [2][4] parity keys (64B)
  float* scd = (float*)(skey + 8);      // [2][4][4] parity coords (128B)
  int* sel = (int*)(scd + 32);          // [CHS]
  const float* pb = pos + (size_t)bid * NN * 3;
  for (int i = tid; i < NN; i += 256) {
    px[i] = pb[3 * i + 0];
    py[i] = pb[3 * i + 1];
    pz[i] = pb[3 * i + 2];
  }
  if (chunk == 0) {
    #pragma unroll
    for (int kk = 0; kk < 4; ++kk)
      batch_out[bid * SSS + kk * 256 + tid] = (float)bid;
  }
  __syncthreads();

  float qx[16], qy[16], qz[16], md[16];
  #pragma unroll
  for (int j = 0; j < 16; ++j) {
    const int i = j * 256 + tid;
    qx[j] = px[i]; qy[j] = py[i]; qz[j] = pz[i];
    asm volatile("" : "+v"(qx[j]), "+v"(qy[j]), "+v"(qz[j]));
    md[j] = __builtin_inff();
  }
  int last, tb;
  const int cbase = chunk * CHS;
  const int te = cbase + CHS;
  float cxr, cyr, czr;
  if (chunk == 0) {
    last = 0; tb = 1;
    cxr = px[0]; cyr = py[0]; czr = pz[0];
    if (tid == 0) {
      fps_idx[bid * SSS] = 0;
      pos_out[(size_t)bid * SSS * 3 + 0] = cxr;
      pos_out[(size_t)bid * SSS * 3 + 1] = cyr;
      pos_out[(size_t)bid * SSS * 3 + 2] = czr;
    }
  } else {
    #pragma unroll
    for (int j = 0; j < 16; ++j) md[j] = md_ws[bid * 4096 + j * 256 + tid];
    last = last_ws[bid]; tb = cbase;
    cxr = px[last]; cyr = py[last]; czr = pz[last];
  }

  for (int t = tb; t < te; ++t) {
    // md update vs register-carried center
    #pragma unroll
    for (int j = 0; j < 16; ++j)
      md[j] = fminf(md[j], d2_exact(qx[j], qy[j], qz[j], cxr, cyr, czr));
    // depth-4 fmax tree + equality mask + ctz == serial strict-> (lowest j among maxima)
    float t8[8], t4[4], t2[2];
    #pragma unroll
    for (int j = 0; j < 8; ++j) t8[j] = fmaxf(md[j], md[j + 8]);
    #pragma unroll
    for (int j = 0; j < 4; ++j) t4[j] = fmaxf(t8[j], t8[j + 4]);
    t2[0] = fmaxf(t4[0], t4[2]); t2[1] = fmaxf(t4[1], t4[3]);
    const float bv = fmaxf(t2[0], t2[1]);
    unsigned mask = 0u;
    #pragma unroll
    for (int j = 0; j < 16; ++j) mask |= (md[j] == bv) ? (1u << j) : 0u;
    const int bj = __builtin_ctz(mask);
    // key = (valbits<<32) | ~idx : u64 max == (max val, lowest idx) == jnp.argmax
    const unsigned myklo = ~(unsigned)(bj * 256 + tid);
    const unsigned mykhi = __float_as_uint(bv);
    unsigned klo = myklo, khi = mykhi;
    // DPP wavefront max-reduce to lane 63 (round-7 proven)
#define FPS_DPP_STAGE(CTRL, RMASK)                                                            \
    {                                                                                          \
      unsigned slo = (unsigned)__builtin_amdgcn_update_dpp(0, (int)klo, CTRL, RMASK, 0xf, true); \
      unsigned shi = (unsigned)__builtin_amdgcn_update_dpp(0, (int)khi, CTRL, RMASK, 0xf, true); \
      if ((((u64)shi << 32) | slo) > (((u64)khi << 32) | klo)) { khi = shi; klo = slo; }       \
    }
    FPS_DPP_STAGE(0x111, 0xf)  // row_shr:1
    FPS_DPP_STAGE(0x112, 0xf)  // row_shr:2
    FPS_DPP_STAGE(0x114, 0xf)  // row_shr:4
    FPS_DPP_STAGE(0x118, 0xf)  // row_shr:8
    FPS_DPP_STAGE(0x142, 0xa)  // row_bcast:15
    FPS_DPP_STAGE(0x143, 0xc)  // row_bcast:31 -> lane63 = wave max
#undef FPS_DPP_STAGE
    // broadcast wave winner; the unique owning lane writes key+coords to the wave slot
    const unsigned wlo = (unsigned)__builtin_amdgcn_readlane((int)klo, 63);
    const unsigned whi = (unsigned)__builtin_amdgcn_readlane((int)khi, 63);
    const int par = (t & 1) * 4;
    if (myklo == wlo && mykhi == whi) {
      const int w = par + (tid >> 6);
      skey[w] = ((u64)whi << 32) | wlo;
      scd[w * 4 + 0] = qx[bj];
      scd[w * 4 + 1] = qy[bj];
      scd[w * 4 + 2] = qz[bj];
    }
    __syncthreads();  // single barrier/step (parity buffers kill the WAR hazard)
    const u64 k0 = skey[par + 0], k1 = skey[par + 1], k2 = skey[par + 2], k3 = skey[par + 3];
    const float a0x = scd[(par + 0) * 4], a0y = scd[(par + 0) * 4 + 1], a0z = scd[(par + 0) * 4 + 2];
    const float a1x = scd[(par + 1) * 4], a1y = scd[(par + 1) * 4 + 1], a1z = scd[(par + 1) * 4 + 2];
    const float a2x = scd[(par + 2) * 4], a2y = scd[(par + 2) * 4 + 1], a2z = scd[(par + 2) * 4 + 2];
    const float a3x = scd[(par + 3) * 4], a3y = scd[(par + 3) * 4 + 1], a3z = scd[(par + 3) * 4 + 2];
    const bool s01 = k1 > k0;
    const u64 ka = s01 ? k1 : k0;
    const float bx0 = s01 ? a1x : a0x, by0 = s01 ? a1y : a0y, bz0 = s01 ? a1z : a0z;
    const bool s23 = k3 > k2;
    const u64 kb = s23 ? k3 : k2;
    const float bx1 = s23 ? a3x : a2x, by1 = s23 ? a3y : a2y, bz1 = s23 ? a3z : a2z;
    const bool sab = kb > ka;
    const u64 win = sab ? kb : ka;
    cxr = sab ? bx1 : bx0; cyr = sab ? by1 : by0; czr = sab ? bz1 : bz0;
    last = (int)(~(unsigned)(win & 0xffffffffull));
    if (tid == 0) sel[t - cbase] = last;
  }

  // flush fps_idx + pos_out for this chunk (coalesced, off the critical path)
  __syncthreads();
  for (int e = tid; e < CHS; e += 256) {
    const int t2 = cbase + e;
    if (t2 == 0) continue;
    const int idx = sel[e];
    fps_idx[bid * SSS + t2] = idx;
    pos_out[((size_t)bid * SSS + t2) * 3 + 0] = px[idx];
    pos_out[((size_t)bid * SSS + t2) * 3 + 1] = py[idx];
    pos_out[((size_t)bid * SSS + t2) * 3 + 2] = pz[idx];
  }
  if (chunk == 0) {
    #pragma unroll
    for (int j = 0; j < 16; ++j) md_ws[bid * 4096 + j * 256 + tid] = md[j];
    if (tid == 0) last_ws[bid] = last;
  }
}

// ---------------- y1 role: y1 = bf16(x @ W1[0:64,:]), XCD-affine (round-16 proven) ----------------
__device__ __forceinline__ void y1_role(int j, int tid,
                                        const float* __restrict__ x,
                                        const float* __restrict__ W1,
                                        unsigned short* __restrict__ y1,
                                        char* smem) {
  float* sW = (float*)smem;             // [64][128] 32KB
  float* sx = (float*)(smem + 32768);   // [8][64] 2KB
  const int cloud = ((j >> 12) << 3) | (j & 7);
  const int local = (j >> 3) & 511;
  const int p0 = cloud * NN + local * 8;
  for (int e = tid; e < CINN * HIDD; e += 256) sW[e] = W1[e];
  for (int e = tid; e < 8 * CINN; e += 256) sx[e] = x[(size_t)p0 * CINN + e];
  __syncthreads();
  const int h = tid & 127;
  const int pg = (tid >> 7) * 4;
  float a0 = 0.f, a1 = 0.f, a2 = 0.f, a3 = 0.f;
  for (int c = 0; c < CINN; ++c) {
    const float w = sW[c * HIDD + h];
    a0 = fmaf(sx[(pg + 0) * CINN + c], w, a0);
    a1 = fmaf(sx[(pg + 1) * CINN + c], w, a1);
    a2 = fmaf(sx[(pg + 2) * CINN + c], w, a2);
    a3 = fmaf(sx[(pg + 3) * CINN + c], w, a3);
  }
  y1[(size_t)(p0 + pg + 0) * HIDD + h] = f2bf(a0);
  y1[(size_t)(p0 + pg + 1) * HIDD + h] = f2bf(a1);
  y1[(size_t)(p0 + pg + 2) * HIDD + h] = f2bf(a2);
  y1[(size_t)(p0 + pg + 3) * HIDD + h] = f2bf(a3);
}

// ---------------- bq role: 8 centers/block, unrolled global scan (round-14 proven) ----------------
__device__ __forceinline__ void bq_role(int cc, int i, int tid,
                                        const float* __restrict__ pos,
                                        const int* __restrict__ fps_idx,
                                        int* __restrict__ nbr,
                                        int* __restrict__ cnt,
                                        char* smem) {
  const int b = i >> 6;                        // 64 blocks per cloud per half (CHS=512)
  const int t0 = cc * CHS + (i & 63) * 8;
  const int gbase = b * SSS + t0;
  float* cd = (float*)smem;                    // [8][MAXC]
  int*   ci = (int*)(smem + 10240);            // [8][MAXC]
  int*   ctr = (int*)(smem + 20480);           // [8]
  int*   scn = ctr + 8;                        // [8]
  float* cctr = (float*)(scn + 8);             // [8][3]

  const float* pb = pos + (size_t)b * NN * 3;
  if (tid < 8) { ctr[tid] = 0; scn[tid] = 0; }
  if (tid < 8) {
    const int cp = fps_idx[gbase + tid];
    cctr[tid * 3 + 0] = pb[cp * 3 + 0];
    cctr[tid * 3 + 1] = pb[cp * 3 + 1];
    cctr[tid * 3 + 2] = pb[cp * 3 + 2];
  }
  __syncthreads();
  float cx[8], cy[8], cz[8];
  #pragma unroll
  for (int c = 0; c < 8; ++c) {
    cx[c] = cctr[c * 3 + 0]; cy[c] = cctr[c * 3 + 1]; cz[c] = cctr[c * 3 + 2];
  }
  #pragma unroll 4
  for (int s2 = 0; s2 < 16; ++s2) {
    const int p = s2 * 256 + tid;
    const float x = pb[3 * p + 0], y = pb[3 * p + 1], z = pb[3 * p + 2];
    #pragma unroll
    for (int c = 0; c < 8; ++c) {
      const float d2 = d2_exact(x, y, z, cx[c], cy[c], cz[c]);
      if (d2 <= 0.04f) {
        const int slot = atomicAdd(&ctr[c], 1);
        if (slot < MAXC) { cd[c * MAXC + slot] = d2; ci[c * MAXC + slot] = p; }
      }
    }
  }
  __syncthreads();
  // exact lex-rank (d2, idx) top-K == lax.top_k tie-break; order-independent
  #pragma unroll 1
  for (int c = 0; c < 8; ++c) {
    const int C = min(ctr[c], MAXC);
    for (int j = tid; j < C; j += 256) {
      const float dj = cd[c * MAXC + j];
      const int ij = ci[c * MAXC + j];
      int rank = 0;
      for (int m = 0; m < C; ++m) {
        const float dm = cd[c * MAXC + m];
        const int im = ci[c * MAXC + m];
        rank += (dm < dj || (dm == dj && im < ij)) ? 1 : 0;
      }
      if (rank < KKK) nbr[(size_t)(gbase + c) * KKK + atomicAdd(&scn[c], 1)] = ij;
    }
  }
  __syncthreads();
  if (tid < 8) cnt[gbase + tid] = scn[tid];
}

// ---------------- mlp role: round-16 proven low-VGPR version (unchanged) ----------------
__device__ __forceinline__ void mlp_role(int cc, int m, int tid,
                                         const float* __restrict__ pos,
                                         const unsigned short* __restrict__ y1,
                                         const float* __restrict__ W1,
                                         const float* __restrict__ b1,
                                         const unsigned short* __restrict__ W2t,
                                         const float* __restrict__ b2,
                                         const int* __restrict__ fps_idx,
                                         const int* __restrict__ nbr,
                                         const int* __restrict__ cnt,
                                         float* __restrict__ out,
                                         char* smem) {
  const int b = ((m >> 11) << 3) | (m & 7);
  const int loc = (m >> 3) & 255;
  const int g0 = b * SSS + cc * CHS + loc * 2;
  char* Hb = smem;                        // h1 bf16 swizzled, 32KB
  float* s_ctr = (float*)(smem + 32768);
  int* s_M = (int*)(smem + 32800);
  int* s_pidx = (int*)(smem + 32832);
  float* s_rel = (float*)(smem + 33344);

  const int wv = tid >> 6, ln = tid & 63;
  const int mw = wv >> 1, nw = wv & 1;
  const int lr = ln & 15, lg = ln >> 4;

  if (tid < 2) {
    s_M[tid] = min(cnt[g0 + tid], KKK);
    const int cp = fps_idx[g0 + tid];
    s_ctr[tid * 3 + 0] = pos[((size_t)b * NN + cp) * 3 + 0];
    s_ctr[tid * 3 + 1] = pos[((size_t)b * NN + cp) * 3 + 1];
    s_ctr[tid * 3 + 2] = pos[((size_t)b * NN + cp) * 3 + 2];
  }
  __syncthreads();

  if (tid < 128) {
    const int ci = tid >> 6, k = tid & 63;
    int p = -1;
    float rx = 0.f, ry = 0.f, rz = 0.f;
    if (k < s_M[ci]) {
      p = nbr[(size_t)(g0 + ci) * KKK + k];
      rx = pos[((size_t)b * NN + p) * 3 + 0] - s_ctr[ci * 3 + 0];
      ry = pos[((size_t)b * NN + p) * 3 + 1] - s_ctr[ci * 3 + 1];
      rz = pos[((size_t)b * NN + p) * 3 + 2] - s_ctr[ci * 3 + 2];
    }
    s_pidx[tid] = p;
    s_rel[tid * 3 + 0] = rx; s_rel[tid * 3 + 1] = ry; s_rel[tid * 3 + 2] = rz;
  }
  __syncthreads();

  const float2 b1v = *(const float2*)(b1 + ln * 2);
  const float2 wav = *(const float2*)(W1 + 64 * HIDD + ln * 2);
  const float2 wbv = *(const float2*)(W1 + 65 * HIDD + ln * 2);
  const float2 wcv = *(const float2*)(W1 + 66 * HIDD + ln * 2);
  const int rbase = wv * 32;
  #pragma unroll
  for (int qb = 0; qb < 4; ++qb) {
    unsigned yreg[8];
    #pragma unroll
    for (int rr = 0; rr < 8; ++rr) {
      const int p = s_pidx[rbase + qb * 8 + rr];
      const int pa = p < 0 ? 0 : p;
      yreg[rr] = *(const unsigned*)(y1 + ((size_t)(b * NN + pa)) * HIDD + ln * 2);
    }
    #pragma unroll
    for (int rr = 0; rr < 8; ++rr) {
      const int r = rbase + qb * 8 + rr;
      const int p = s_pidx[r];
      unsigned val = 0u;
      if (p >= 0) {
        const float rx = s_rel[r * 3 + 0], ry = s_rel[r * 3 + 1], rz = s_rel[r * 3 + 2];
        const float y0 = __uint_as_float(yreg[rr] << 16);
        const float y1f = __uint_as_float(yreg[rr] & 0xffff0000u);
        const float v0 = fmaxf(y0 + b1v.x + rx * wav.x + ry * wbv.x + rz * wcv.x, 0.f);
        const float v1 = fmaxf(y1f + b1v.y + rx * wav.y + ry * wbv.y + rz * wcv.y, 0.f);
        val = (unsigned)f2bf(v0) | ((unsigned)f2bf(v1) << 16);
      }
      *(unsigned*)(Hb + r * 256 + ((ln * 4) ^ ((r & 7) << 4))) = val;
    }
  }
  __syncthreads();

  f32x4 zero = {0.f, 0.f, 0.f, 0.f};
  f32x4 acc[4][4];
  #pragma unroll
  for (int mi = 0; mi < 4; ++mi)
    #pragma unroll
    for (int ni = 0; ni < 4; ++ni) acc[mi][ni] = zero;

  #pragma unroll
  for (int ks = 0; ks < 4; ++ks) {
    short8 bfr[4];
    #pragma unroll
    for (int ni = 0; ni < 4; ++ni)
      bfr[ni] = *(const short8*)(W2t + (size_t)(nw * 64 + ni * 16 + lr) * HIDD + ks * 32 + lg * 8);
    short8 af[4];
    #pragma unroll
    for (int mi = 0; mi < 4; ++mi) {
      const int row = mw * 64 + mi * 16 + lr;
      af[mi] = *(const short8*)(Hb + row * 256 + ((ks * 64 + lg * 16) ^ ((row & 7) << 4)));
    }
    #pragma unroll
    for (int mi = 0; mi < 4; ++mi)
      #pragma unroll
      for (int ni = 0; ni < 4; ++ni)
        acc[mi][ni] = __builtin_amdgcn_mfma_f32_16x16x32_bf16(af[mi], bfr[ni], acc[mi][ni], 0, 0, 0);
  }

  const int cId = g0 + mw;
  const int Mc = s_M[mw];
  #pragma unroll
  for (int ni = 0; ni < 4; ++ni) {
    const float b2v = b2[nw * 64 + ni * 16 + lr];
    float cm = 0.f;
    #pragma unroll
    for (int mi = 0; mi < 4; ++mi)
      #pragma unroll
      for (int rr = 0; rr < 4; ++rr) {
        const int k = mi * 16 + lg * 4 + rr;
        const float v = fmaxf(acc[mi][ni][rr] + b2v, 0.f);
        cm = fmaxf(cm, k < Mc ? v : 0.f);
      }
    cm = fmaxf(cm, __shfl_xor(cm, 16, 64));
    cm = fmaxf(cm, __shfl_xor(cm, 32, 64));
    if (ln < 16) out[(size_t)cId * HIDD + nw * 64 + ni * 16 + lr] = cm;
  }
}

// ============ 4 launches: P0 FPSa||y1||W2t, P1 FPSb||bq0, P2 bq1||mlp0, P3 mlp1 ============
__global__ __launch_bounds__(256) void k_phase0(const float* __restrict__ x,
                                                const float* __restrict__ pos,
                                                const float* __restrict__ W1,
                                                const float* __restrict__ W2,
                                                unsigned short* __restrict__ W2t,
                                                int* __restrict__ fps_idx,
                                                unsigned short* __restrict__ y1,
                                                float* __restrict__ md_ws,
                                                int* __restrict__ last_ws,
                                                float* __restrict__ pos_out,
                                                float* __restrict__ batch_out) {
  __shared__ __align__(16) char smem[51392];
  const int bid = blockIdx.x, tid = threadIdx.x;
  if (bid < BB) {
    fps_role(0, bid, tid, pos, fps_idx, md_ws, last_ws, pos_out, batch_out, smem);
  } else if (bid < 16 + 8192) {
    y1_role(bid - 16, tid, x, W1, y1, smem);
  } else {
    for (int e = tid; e < HIDD * HIDD; e += 256) {
      const int n = e >> 7, hh = e & 127;
      W2t[e] = f2bf(W2[hh * HIDD + n]);   // W2t[n][h]
    }
  }
}

__global__ __launch_bounds__(256) void k_phase1(const float* __restrict__ pos,
                                                int* __restrict__ fps_idx,
                                                int* __restrict__ cnt,
                                                int* __restrict__ nbr,
                                                float* __restrict__ md_ws,
                                                int* __restrict__ last_ws,
                                                float* __restrict__ pos_out,
                                                float* __restrict__ batch_out) {
  __shared__ __align__(16) char smem[51392];
  const int bid = blockIdx.x, tid = threadIdx.x;
  if (bid < BB) {
    fps_role(1, bid, tid, pos, fps_idx, md_ws, last_ws, pos_out, batch_out, smem);
  } else {
    bq_role(0, bid - 16, tid, pos, fps_idx, nbr, cnt, smem);
  }
}

// P2: bq chunk 1 || mlp chunk 0 (no FPS to protect; mutually independent)
__global__ __launch_bounds__(256) void k_phase2(const float* __restrict__ pos,
                                                const unsigned short* __restrict__ y1,
                                                const float* __restrict__ W1,
                                                const float* __restrict__ b1,
                                                const unsigned short* __restrict__ W2t,
                                                const float* __restrict__ b2,
                                                int* __restrict__ fps_idx,
                                                int* __restrict__ nbr,
                                                int* __restrict__ cnt,
                                                float* __restrict__ out) {
  __shared__ __align__(16) char smem[34944];
  const int bid = blockIdx.x, tid = threadIdx.x;
  if (bid < 1024) {
    bq_role(1, bid, tid, pos, fps_idx, nbr, cnt, smem);
  } else {
    mlp_role(0, bid - 1024, tid, pos, y1, W1, b1, W2t, b2, fps_idx, nbr, cnt, out, smem);
  }
}

__global__ __launch_bounds__(256) void k_phase3(const float* __restrict__ pos,
                                                const unsigned short* __restrict__ y1,
                                                const float* __restrict__ W1,
                                                const float* __restrict__ b1,
                                                const unsigned short* __restrict__ W2t,
                                                const float* __restrict__ b2,
                                                const int* __restrict__ fps_idx,
                                                const int* __restrict__ nbr,
                                                const int* __restrict__ cnt,
                                                float* __restrict__ out) {
  __shared__ __align__(16) char smem[34944];
  mlp_role(1, blockIdx.x, threadIdx.x, pos, y1, W1, b1, W2t, b2,
           fps_idx, nbr, cnt, out, smem);
}

extern "C" void kernel_launch(void* const* d_in, const int* in_sizes, int n_in,
                              void* d_out, int out_size, void* d_ws, size_t ws_size,
                              hipStream_t stream) {
  const float* x   = (const float*)d_in[0];
  const float* pos = (const float*)d_in[1];
  const float* W1  = (const float*)d_in[3];
  const float* b1  = (const float*)d_in[4];
  const float* W2  = (const float*)d_in[5];
  const float* b2  = (const float*)d_in[6];

  float* out       = (float*)d_out;                   // [B*S, HID]
  float* pos_out   = out + (size_t)BB * SSS * HIDD;   // [B*S, 3]
  float* batch_out = pos_out + (size_t)BB * SSS * 3;  // [B*S]

  int* fps_idx        = (int*)d_ws;                                          // 64 KB
  int* cnt            = (int*)((char*)d_ws + 65536);                         // 64 KB
  unsigned short* W2t = (unsigned short*)((char*)d_ws + 131072);             // 32 KB
  int* last_ws        = (int*)((char*)d_ws + 163840);                        // 64 B
  int* nbr            = (int*)((char*)d_ws + 262144);                        // 4 MB
  unsigned short* y1  = (unsigned short*)((char*)d_ws + 262144 + 4194304);   // 16 MB (bf16)
  float* md_ws        = (float*)((char*)d_ws + 262144 + 4194304 + 33554432); // 256 KB

  k_phase0<<<16 + 8192 + 1, 256, 0, stream>>>(x, pos, W1, W2, W2t, fps_idx, y1,
                                              md_ws, last_ws, pos_out, batch_out);
  k_phase1<<<16 + 1024, 256, 0, stream>>>(pos, fps_idx, cnt, nbr,
                                          md_ws, last_ws, pos_out, batch_out);
  k_phase2<<<1024 + 4096, 256, 0, stream>>>(pos, y1, W1, b1, W2t, b2,
                                            fps_idx, nbr, cnt, out);
  k_phase3<<<4096, 256, 0, stream>>>(pos, y1, W1, b1, W2t, b2,
                                     fps_idx, nbr, cnt, out);
}

// Round 19
// 801.011 us; speedup vs baseline: 1.4089x; 1.3629x over previous
//
#include <hip/hip_runtime.h>
#include <cstdint>
#include <cstddef>

#define BB   16
#define NN   4096
#define CINN 64
#define KKK  64
#define HIDD 128
#define SSS  1024
#define MAXC 320
#define NCH  2
#define CHS  512   // FPS steps / centers per half-chunk

typedef __attribute__((ext_vector_type(8))) short short8;
typedef __attribute__((ext_vector_type(4))) float f32x4;
typedef unsigned long long u64;

// Exact f32 squared distance, numpy-style: ((dx*dx + dy*dy) + dz*dz), no FMA contraction.
// MUST stay bit-identical (absmax 0.0 in round 1 proved selection equivalence).
__device__ __forceinline__ float d2_exact(float ax, float ay, float az,
                                          float bx, float by, float bz) {
  float dx = __fsub_rn(ax, bx);
  float dy = __fsub_rn(ay, by);
  float dz = __fsub_rn(az, bz);
  return __fadd_rn(__fadd_rn(__fmul_rn(dx, dx), __fmul_rn(dy, dy)), __fmul_rn(dz, dz));
}

// f32 -> bf16 round-to-nearest-even (no NaN inputs here)
__device__ __forceinline__ unsigned short f2bf(float f) {
  unsigned u = __float_as_uint(f);
  return (unsigned short)((u + 0x7fffu + ((u >> 16) & 1u)) >> 16);
}

// ---------------- FPS role: round-16 PROVEN version (298us/phase), reverted verbatim.
// LDS sel buffer + chunk flush; serial bv/bj chain; u64-DPP reduce; px[last] gather. ----------------
__device__ __forceinline__ void fps_role(int chunk, int bid, int tid,
                                         const float* __restrict__ pos,
                                         int* __restrict__ fps_idx,
                                         float* __restrict__ md_ws,
                                         int* __restrict__ last_ws,
                                         float* __restrict__ pos_out,
                                         float* __restrict__ batch_out,
                                         char* smem) {
  __builtin_amdgcn_s_setprio(3);  // protect the serial critical path from co-resident waves
  float* px = (float*)smem;
  float* py = px + NN;
  float* pz = py + NN;
  u64* slots = (u64*)(pz + NN);      // [2][4] parity-double-buffered wave leaders (64B)
  int* sel = (int*)(slots + 8);      // [CHS] selected indices of this chunk
  const float* pb = pos + (size_t)bid * NN * 3;
  for (int i = tid; i < NN; i += 256) {
    px[i] = pb[3 * i + 0];
    py[i] = pb[3 * i + 1];
    pz[i] = pb[3 * i + 2];
  }
  if (chunk == 0) {
    #pragma unroll
    for (int kk = 0; kk < 4; ++kk)
      batch_out[bid * SSS + kk * 256 + tid] = (float)bid;
  }
  __syncthreads();

  float qx[16], qy[16], qz[16], md[16];
  #pragma unroll
  for (int j = 0; j < 16; ++j) {
    const int i = j * 256 + tid;
    qx[j] = px[i]; qy[j] = py[i]; qz[j] = pz[i];
    asm volatile("" : "+v"(qx[j]), "+v"(qy[j]), "+v"(qz[j]));
    md[j] = __builtin_inff();
  }
  int last, tb;
  const int cbase = chunk * CHS;
  const int te = cbase + CHS;
  if (chunk == 0) {
    last = 0; tb = 1;
    if (tid == 0) {
      fps_idx[bid * SSS] = 0;
      pos_out[(size_t)bid * SSS * 3 + 0] = px[0];
      pos_out[(size_t)bid * SSS * 3 + 1] = py[0];
      pos_out[(size_t)bid * SSS * 3 + 2] = pz[0];
    }
  } else {
    #pragma unroll
    for (int j = 0; j < 16; ++j) md[j] = md_ws[bid * 4096 + j * 256 + tid];
    last = last_ws[bid]; tb = cbase;
  }

  for (int t = tb; t < te; ++t) {
    const float lx = px[last], ly = py[last], lz = pz[last];  // LDS broadcast
    float bv = -1.f;
    int bj = 0;
    #pragma unroll
    for (int j = 0; j < 16; ++j) {
      const float d = d2_exact(qx[j], qy[j], qz[j], lx, ly, lz);
      md[j] = fminf(md[j], d);
      if (md[j] > bv) { bv = md[j]; bj = j; }  // strict > : lowest j among ties
    }
    // key = (valbits<<32) | ~idx : u64 max == (max val, lowest idx) == jnp.argmax
    unsigned klo = ~(unsigned)(bj * 256 + tid);
    unsigned khi = __float_as_uint(bv);
    // DPP wavefront max-reduce to lane 63 (round-7 proven).
#define FPS_DPP_STAGE(CTRL, RMASK)                                                            \
    {                                                                                          \
      unsigned slo = (unsigned)__builtin_amdgcn_update_dpp(0, (int)klo, CTRL, RMASK, 0xf, true); \
      unsigned shi = (unsigned)__builtin_amdgcn_update_dpp(0, (int)khi, CTRL, RMASK, 0xf, true); \
      if ((((u64)shi << 32) | slo) > (((u64)khi << 32) | klo)) { khi = shi; klo = slo; }       \
    }
    FPS_DPP_STAGE(0x111, 0xf)  // row_shr:1
    FPS_DPP_STAGE(0x112, 0xf)  // row_shr:2
    FPS_DPP_STAGE(0x114, 0xf)  // row_shr:4
    FPS_DPP_STAGE(0x118, 0xf)  // row_shr:8
    FPS_DPP_STAGE(0x142, 0xa)  // row_bcast:15
    FPS_DPP_STAGE(0x143, 0xc)  // row_bcast:31 -> lane63 = wave max
#undef FPS_DPP_STAGE
    u64* sl = slots + (t & 1) * 4;
    if ((tid & 63) == 63) sl[tid >> 6] = ((u64)khi << 32) | klo;
    __syncthreads();  // single barrier/step; LDS-only traffic (no vmcnt drain)
    u64 mm = sl[0];
    #pragma unroll
    for (int w = 1; w < 4; ++w) mm = sl[w] > mm ? sl[w] : mm;
    last = (int)(~(unsigned)(mm & 0xffffffffull));
    if (tid == 0) sel[t - cbase] = last;   // buffer selection in LDS
  }

  // flush fps_idx + pos_out for this chunk (coalesced, off the critical path)
  __syncthreads();
  for (int e = tid; e < CHS; e += 256) {
    const int t2 = cbase + e;
    if (t2 == 0) continue;  // written at init
    const int idx = sel[e];
    fps_idx[bid * SSS + t2] = idx;
    pos_out[((size_t)bid * SSS + t2) * 3 + 0] = px[idx];
    pos_out[((size_t)bid * SSS + t2) * 3 + 1] = py[idx];
    pos_out[((size_t)bid * SSS + t2) * 3 + 2] = pz[idx];
  }
  if (chunk == 0) {
    #pragma unroll
    for (int j = 0; j < 16; ++j) md_ws[bid * 4096 + j * 256 + tid] = md[j];
    if (tid == 0) last_ws[bid] = last;
  }
}

// ---------------- y1 role: y1 = bf16(x @ W1[0:64,:]), XCD-affine (round-16 proven) ----------------
__device__ __forceinline__ void y1_role(int j, int tid,
                                        const float* __restrict__ x,
                                        const float* __restrict__ W1,
                                        unsigned short* __restrict__ y1,
                                        char* smem) {
  float* sW = (float*)smem;             // [64][128] 32KB
  float* sx = (float*)(smem + 32768);   // [8][64] 2KB
  const int cloud = ((j >> 12) << 3) | (j & 7);
  const int local = (j >> 3) & 511;
  const int p0 = cloud * NN + local * 8;
  for (int e = tid; e < CINN * HIDD; e += 256) sW[e] = W1[e];
  for (int e = tid; e < 8 * CINN; e += 256) sx[e] = x[(size_t)p0 * CINN + e];
  __syncthreads();
  const int h = tid & 127;
  const int pg = (tid >> 7) * 4;
  float a0 = 0.f, a1 = 0.f, a2 = 0.f, a3 = 0.f;
  for (int c = 0; c < CINN; ++c) {
    const float w = sW[c * HIDD + h];
    a0 = fmaf(sx[(pg + 0) * CINN + c], w, a0);
    a1 = fmaf(sx[(pg + 1) * CINN + c], w, a1);
    a2 = fmaf(sx[(pg + 2) * CINN + c], w, a2);
    a3 = fmaf(sx[(pg + 3) * CINN + c], w, a3);
  }
  y1[(size_t)(p0 + pg + 0) * HIDD + h] = f2bf(a0);
  y1[(size_t)(p0 + pg + 1) * HIDD + h] = f2bf(a1);
  y1[(size_t)(p0 + pg + 2) * HIDD + h] = f2bf(a2);
  y1[(size_t)(p0 + pg + 3) * HIDD + h] = f2bf(a3);
}

// ---------------- bq role: 8 centers/block, unrolled global scan (round-14 proven) ----------------
__device__ __forceinline__ void bq_role(int cc, int i, int tid,
                                        const float* __restrict__ pos,
                                        const int* __restrict__ fps_idx,
                                        int* __restrict__ nbr,
                                        int* __restrict__ cnt,
                                        char* smem) {
  const int b = i >> 6;                        // 64 blocks per cloud per half (CHS=512)
  const int t0 = cc * CHS + (i & 63) * 8;
  const int gbase = b * SSS + t0;
  float* cd = (float*)smem;                    // [8][MAXC]
  int*   ci = (int*)(smem + 10240);            // [8][MAXC]
  int*   ctr = (int*)(smem + 20480);           // [8]
  int*   scn = ctr + 8;                        // [8]
  float* cctr = (float*)(scn + 8);             // [8][3]

  const float* pb = pos + (size_t)b * NN * 3;
  if (tid < 8) { ctr[tid] = 0; scn[tid] = 0; }
  if (tid < 8) {
    const int cp = fps_idx[gbase + tid];
    cctr[tid * 3 + 0] = pb[cp * 3 + 0];
    cctr[tid * 3 + 1] = pb[cp * 3 + 1];
    cctr[tid * 3 + 2] = pb[cp * 3 + 2];
  }
  __syncthreads();
  float cx[8], cy[8], cz[8];
  #pragma unroll
  for (int c = 0; c < 8; ++c) {
    cx[c] = cctr[c * 3 + 0]; cy[c] = cctr[c * 3 + 1]; cz[c] = cctr[c * 3 + 2];
  }
  #pragma unroll 4
  for (int s2 = 0; s2 < 16; ++s2) {
    const int p = s2 * 256 + tid;
    const float x = pb[3 * p + 0], y = pb[3 * p + 1], z = pb[3 * p + 2];
    #pragma unroll
    for (int c = 0; c < 8; ++c) {
      const float d2 = d2_exact(x, y, z, cx[c], cy[c], cz[c]);
      if (d2 <= 0.04f) {
        const int slot = atomicAdd(&ctr[c], 1);
        if (slot < MAXC) { cd[c * MAXC + slot] = d2; ci[c * MAXC + slot] = p; }
      }
    }
  }
  __syncthreads();
  // exact lex-rank (d2, idx) top-K == lax.top_k tie-break; order-independent
  #pragma unroll 1
  for (int c = 0; c < 8; ++c) {
    const int C = min(ctr[c], MAXC);
    for (int j = tid; j < C; j += 256) {
      const float dj = cd[c * MAXC + j];
      const int ij = ci[c * MAXC + j];
      int rank = 0;
      for (int m = 0; m < C; ++m) {
        const float dm = cd[c * MAXC + m];
        const int im = ci[c * MAXC + m];
        rank += (dm < dj || (dm == dj && im < ij)) ? 1 : 0;
      }
      if (rank < KKK) nbr[(size_t)(gbase + c) * KKK + atomicAdd(&scn[c], 1)] = ij;
    }
  }
  __syncthreads();
  if (tid < 8) cnt[gbase + tid] = scn[tid];
}

// ---------------- mlp role: round-16 proven low-VGPR version (unchanged) ----------------
__device__ __forceinline__ void mlp_role(int cc, int m, int tid,
                                         const float* __restrict__ pos,
                                         const unsigned short* __restrict__ y1,
                                         const float* __restrict__ W1,
                                         const float* __restrict__ b1,
                                         const unsigned short* __restrict__ W2t,
                                         const float* __restrict__ b2,
                                         const int* __restrict__ fps_idx,
                                         const int* __restrict__ nbr,
                                         const int* __restrict__ cnt,
                                         float* __restrict__ out,
                                         char* smem) {
  const int b = ((m >> 11) << 3) | (m & 7);   // XCD-affine cloud mapping
  const int loc = (m >> 3) & 255;
  const int g0 = b * SSS + cc * CHS + loc * 2;
  char* Hb = smem;                        // h1 bf16 swizzled, 32KB
  float* s_ctr = (float*)(smem + 32768);
  int* s_M = (int*)(smem + 32800);
  int* s_pidx = (int*)(smem + 32832);
  float* s_rel = (float*)(smem + 33344);

  const int wv = tid >> 6, ln = tid & 63;
  const int mw = wv >> 1, nw = wv & 1;
  const int lr = ln & 15, lg = ln >> 4;

  if (tid < 2) {
    s_M[tid] = min(cnt[g0 + tid], KKK);
    const int cp = fps_idx[g0 + tid];
    s_ctr[tid * 3 + 0] = pos[((size_t)b * NN + cp) * 3 + 0];
    s_ctr[tid * 3 + 1] = pos[((size_t)b * NN + cp) * 3 + 1];
    s_ctr[tid * 3 + 2] = pos[((size_t)b * NN + cp) * 3 + 2];
  }
  __syncthreads();

  // cooperative precompute: row t -> neighbor index + rel (kills the per-row nbr->pos chain)
  if (tid < 128) {
    const int ci = tid >> 6, k = tid & 63;
    int p = -1;
    float rx = 0.f, ry = 0.f, rz = 0.f;
    if (k < s_M[ci]) {
      p = nbr[(size_t)(g0 + ci) * KKK + k];
      rx = pos[((size_t)b * NN + p) * 3 + 0] - s_ctr[ci * 3 + 0];
      ry = pos[((size_t)b * NN + p) * 3 + 1] - s_ctr[ci * 3 + 1];
      rz = pos[((size_t)b * NN + p) * 3 + 2] - s_ctr[ci * 3 + 2];
    }
    s_pidx[tid] = p;
    s_rel[tid * 3 + 0] = rx; s_rel[tid * 3 + 1] = ry; s_rel[tid * 3 + 2] = rz;
  }
  __syncthreads();

  const float2 b1v = *(const float2*)(b1 + ln * 2);
  const float2 wav = *(const float2*)(W1 + 64 * HIDD + ln * 2);
  const float2 wbv = *(const float2*)(W1 + 65 * HIDD + ln * 2);
  const float2 wcv = *(const float2*)(W1 + 66 * HIDD + ln * 2);
  const int rbase = wv * 32;
  // four register batches of 8: loads issue before consumers, low live-register count
  #pragma unroll
  for (int qb = 0; qb < 4; ++qb) {
    unsigned yreg[8];
    #pragma unroll
    for (int rr = 0; rr < 8; ++rr) {
      const int p = s_pidx[rbase + qb * 8 + rr];
      const int pa = p < 0 ? 0 : p;
      yreg[rr] = *(const unsigned*)(y1 + ((size_t)(b * NN + pa)) * HIDD + ln * 2);
    }
    #pragma unroll
    for (int rr = 0; rr < 8; ++rr) {
      const int r = rbase + qb * 8 + rr;
      const int p = s_pidx[r];
      unsigned val = 0u;
      if (p >= 0) {
        const float rx = s_rel[r * 3 + 0], ry = s_rel[r * 3 + 1], rz = s_rel[r * 3 + 2];
        const float y0 = __uint_as_float(yreg[rr] << 16);          // bf2f(low half)
        const float y1f = __uint_as_float(yreg[rr] & 0xffff0000u); // bf2f(high half)
        const float v0 = fmaxf(y0 + b1v.x + rx * wav.x + ry * wbv.x + rz * wcv.x, 0.f);
        const float v1 = fmaxf(y1f + b1v.y + rx * wav.y + ry * wbv.y + rz * wcv.y, 0.f);
        val = (unsigned)f2bf(v0) | ((unsigned)f2bf(v1) << 16);
      }
      *(unsigned*)(Hb + r * 256 + ((ln * 4) ^ ((r & 7) << 4))) = val;
    }
  }
  __syncthreads();

  // MFMA: wave (mw=center, nw=col-half); 4x4 16x16 tiles; K=128 in 4 steps of 32.
  // B-fragments loaded per-ks from global W2t (L2-broadcast) to keep live VGPRs low.
  f32x4 zero = {0.f, 0.f, 0.f, 0.f};
  f32x4 acc[4][4];
  #pragma unroll
  for (int mi = 0; mi < 4; ++mi)
    #pragma unroll
    for (int ni = 0; ni < 4; ++ni) acc[mi][ni] = zero;

  #pragma unroll
  for (int ks = 0; ks < 4; ++ks) {
    short8 bfr[4];
    #pragma unroll
    for (int ni = 0; ni < 4; ++ni)
      bfr[ni] = *(const short8*)(W2t + (size_t)(nw * 64 + ni * 16 + lr) * HIDD + ks * 32 + lg * 8);
    short8 af[4];
    #pragma unroll
    for (int mi = 0; mi < 4; ++mi) {
      const int row = mw * 64 + mi * 16 + lr;
      af[mi] = *(const short8*)(Hb + row * 256 + ((ks * 64 + lg * 16) ^ ((row & 7) << 4)));
    }
    #pragma unroll
    for (int mi = 0; mi < 4; ++mi)
      #pragma unroll
      for (int ni = 0; ni < 4; ++ni)
        acc[mi][ni] = __builtin_amdgcn_mfma_f32_16x16x32_bf16(af[mi], bfr[ni], acc[mi][ni], 0, 0, 0);
  }

  // epilogue: relu(acc+b2), mask k>=M to 0 (relu>=0, k=0 valid => exact), max over k
  const int cId = g0 + mw;
  const int Mc = s_M[mw];
  #pragma unroll
  for (int ni = 0; ni < 4; ++ni) {
    const float b2v = b2[nw * 64 + ni * 16 + lr];
    float cm = 0.f;
    #pragma unroll
    for (int mi = 0; mi < 4; ++mi)
      #pragma unroll
      for (int rr = 0; rr < 4; ++rr) {
        const int k = mi * 16 + lg * 4 + rr;   // C layout: col=lane&15, row=(lane>>4)*4+reg
        const float v = fmaxf(acc[mi][ni][rr] + b2v, 0.f);
        cm = fmaxf(cm, k < Mc ? v : 0.f);
      }
    cm = fmaxf(cm, __shfl_xor(cm, 16, 64));
    cm = fmaxf(cm, __shfl_xor(cm, 32, 64));
    if (ln < 16) out[(size_t)cId * HIDD + nw * 64 + ni * 16 + lr] = cm;
  }
}

// ============ 4 launches: P0 FPSa||y1||W2t, P1 FPSb||bq0, P2 bq1||mlp0, P3 mlp1 ============
__global__ __launch_bounds__(256) void k_phase0(const float* __restrict__ x,
                                                const float* __restrict__ pos,
                                                const float* __restrict__ W1,
                                                const float* __restrict__ W2,
                                                unsigned short* __restrict__ W2t,
                                                int* __restrict__ fps_idx,
                                                unsigned short* __restrict__ y1,
                                                float* __restrict__ md_ws,
                                                int* __restrict__ last_ws,
                                                float* __restrict__ pos_out,
                                                float* __restrict__ batch_out) {
  __shared__ __align__(16) char smem[51264];
  const int bid = blockIdx.x, tid = threadIdx.x;
  if (bid < BB) {
    fps_role(0, bid, tid, pos, fps_idx, md_ws, last_ws, pos_out, batch_out, smem);
  } else if (bid < 16 + 8192) {
    y1_role(bid - 16, tid, x, W1, y1, smem);
  } else {
    for (int e = tid; e < HIDD * HIDD; e += 256) {
      const int n = e >> 7, hh = e & 127;
      W2t[e] = f2bf(W2[hh * HIDD + n]);   // W2t[n][h]
    }
  }
}

__global__ __launch_bounds__(256) void k_phase1(const float* __restrict__ pos,
                                                int* __restrict__ fps_idx,
                                                int* __restrict__ cnt,
                                                int* __restrict__ nbr,
                                                float* __restrict__ md_ws,
                                                int* __restrict__ last_ws,
                                                float* __restrict__ pos_out,
                                                float* __restrict__ batch_out) {
  __shared__ __align__(16) char smem[51264];
  const int bid = blockIdx.x, tid = threadIdx.x;
  if (bid < BB) {
    fps_role(1, bid, tid, pos, fps_idx, md_ws, last_ws, pos_out, batch_out, smem);
  } else {
    bq_role(0, bid - 16, tid, pos, fps_idx, nbr, cnt, smem);
  }
}

// P2: bq chunk 1 || mlp chunk 0 (no FPS to protect; mutually independent)
__global__ __launch_bounds__(256) void k_phase2(const float* __restrict__ pos,
                                                const unsigned short* __restrict__ y1,
                                                const float* __restrict__ W1,
                                                const float* __restrict__ b1,
                                                const unsigned short* __restrict__ W2t,
                                                const float* __restrict__ b2,
                                                int* __restrict__ fps_idx,
                                                int* __restrict__ nbr,
                                                int* __restrict__ cnt,
                                                float* __restrict__ out) {
  __shared__ __align__(16) char smem[34944];
  const int bid = blockIdx.x, tid = threadIdx.x;
  if (bid < 1024) {
    bq_role(1, bid, tid, pos, fps_idx, nbr, cnt, smem);
  } else {
    mlp_role(0, bid - 1024, tid, pos, y1, W1, b1, W2t, b2, fps_idx, nbr, cnt, out, smem);
  }
}

__global__ __launch_bounds__(256) void k_phase3(const float* __restrict__ pos,
                                                const unsigned short* __restrict__ y1,
                                                const float* __restrict__ W1,
                                                const float* __restrict__ b1,
                                                const unsigned short* __restrict__ W2t,
                                                const float* __restrict__ b2,
                                                const int* __restrict__ fps_idx,
                                                const int* __restrict__ nbr,
                                                const int* __restrict__ cnt,
                                                float* __restrict__ out) {
  __shared__ __align__(16) char smem[34944];
  mlp_role(1, blockIdx.x, threadIdx.x, pos, y1, W1, b1, W2t, b2,
           fps_idx, nbr, cnt, out, smem);
}

extern "C" void kernel_launch(void* const* d_in, const int* in_sizes, int n_in,
                              void* d_out, int out_size, void* d_ws, size_t ws_size,
                              hipStream_t stream) {
  const float* x   = (const float*)d_in[0];
  const float* pos = (const float*)d_in[1];
  const float* W1  = (const float*)d_in[3];
  const float* b1  = (const float*)d_in[4];
  const float* W2  = (const float*)d_in[5];
  const float* b2  = (const float*)d_in[6];

  float* out       = (float*)d_out;                   // [B*S, HID]
  float* pos_out   = out + (size_t)BB * SSS * HIDD;   // [B*S, 3]
  float* batch_out = pos_out + (size_t)BB * SSS * 3;  // [B*S]

  int* fps_idx        = (int*)d_ws;                                          // 64 KB
  int* cnt            = (int*)((char*)d_ws + 65536);                         // 64 KB
  unsigned short* W2t = (unsigned short*)((char*)d_ws + 131072);             // 32 KB
  int* last_ws        = (int*)((char*)d_ws + 163840);                        // 64 B
  int* nbr            = (int*)((char*)d_ws + 262144);                        // 4 MB
  unsigned short* y1  = (unsigned short*)((char*)d_ws + 262144 + 4194304);   // 16 MB (bf16)
  float* md_ws        = (float*)((char*)d_ws + 262144 + 4194304 + 33554432); // 256 KB

  k_phase0<<<16 + 8192 + 1, 256, 0, stream>>>(x, pos, W1, W2, W2t, fps_idx, y1,
                                              md_ws, last_ws, pos_out, batch_out);
  k_phase1<<<16 + 1024, 256, 0, stream>>>(pos, fps_idx, cnt, nbr,
                                          md_ws, last_ws, pos_out, batch_out);
  k_phase2<<<1024 + 4096, 256, 0, stream>>>(pos, y1, W1, b1, W2t, b2,
                                            fps_idx, nbr, cnt, out);
  k_phase3<<<4096, 256, 0, stream>>>(pos, y1, W1, b1, W2t, b2,
                                     fps_idx, nbr, cnt, out);
}

// Round 20
// 796.929 us; speedup vs baseline: 1.4161x; 1.0051x over previous
//
#include <hip/hip_runtime.h>
#include <cstdint>
#include <cstddef>

#define BB   16
#define NN   4096
#define CINN 64
#define KKK  64
#define HIDD 128
#define SSS  1024
#define MAXC 320
#define NCH  2
#define CHS  512   // FPS steps / centers per half-chunk

typedef __attribute__((ext_vector_type(8))) short short8;
typedef __attribute__((ext_vector_type(4))) float f32x4;
typedef unsigned long long u64;

// Exact f32 squared distance, numpy-style: ((dx*dx + dy*dy) + dz*dz), no FMA contraction.
// MUST stay bit-identical (absmax 0.0 in round 1 proved selection equivalence).
__device__ __forceinline__ float d2_exact(float ax, float ay, float az,
                                          float bx, float by, float bz) {
  float dx = __fsub_rn(ax, bx);
  float dy = __fsub_rn(ay, by);
  float dz = __fsub_rn(az, bz);
  return __fadd_rn(__fadd_rn(__fmul_rn(dx, dx), __fmul_rn(dy, dy)), __fmul_rn(dz, dz));
}

// f32 -> bf16 round-to-nearest-even (no NaN inputs here)
__device__ __forceinline__ unsigned short f2bf(float f) {
  unsigned u = __float_as_uint(f);
  return (unsigned short)((u + 0x7fffu + ((u >> 16) & 1u)) >> 16);
}

// ---------------- FPS role: round-16 PROVEN version (298us/phase), unchanged ----------------
__device__ __forceinline__ void fps_role(int chunk, int bid, int tid,
                                         const float* __restrict__ pos,
                                         int* __restrict__ fps_idx,
                                         float* __restrict__ md_ws,
                                         int* __restrict__ last_ws,
                                         float* __restrict__ pos_out,
                                         float* __restrict__ batch_out,
                                         char* smem) {
  __builtin_amdgcn_s_setprio(3);  // protect the serial critical path from co-resident waves
  float* px = (float*)smem;
  float* py = px + NN;
  float* pz = py + NN;
  u64* slots = (u64*)(pz + NN);      // [2][4] parity-double-buffered wave leaders (64B)
  int* sel = (int*)(slots + 8);      // [CHS] selected indices of this chunk
  const float* pb = pos + (size_t)bid * NN * 3;
  for (int i = tid; i < NN; i += 256) {
    px[i] = pb[3 * i + 0];
    py[i] = pb[3 * i + 1];
    pz[i] = pb[3 * i + 2];
  }
  if (chunk == 0) {
    #pragma unroll
    for (int kk = 0; kk < 4; ++kk)
      batch_out[bid * SSS + kk * 256 + tid] = (float)bid;
  }
  __syncthreads();

  float qx[16], qy[16], qz[16], md[16];
  #pragma unroll
  for (int j = 0; j < 16; ++j) {
    const int i = j * 256 + tid;
    qx[j] = px[i]; qy[j] = py[i]; qz[j] = pz[i];
    asm volatile("" : "+v"(qx[j]), "+v"(qy[j]), "+v"(qz[j]));
    md[j] = __builtin_inff();
  }
  int last, tb;
  const int cbase = chunk * CHS;
  const int te = cbase + CHS;
  if (chunk == 0) {
    last = 0; tb = 1;
    if (tid == 0) {
      fps_idx[bid * SSS] = 0;
      pos_out[(size_t)bid * SSS * 3 + 0] = px[0];
      pos_out[(size_t)bid * SSS * 3 + 1] = py[0];
      pos_out[(size_t)bid * SSS * 3 + 2] = pz[0];
    }
  } else {
    #pragma unroll
    for (int j = 0; j < 16; ++j) md[j] = md_ws[bid * 4096 + j * 256 + tid];
    last = last_ws[bid]; tb = cbase;
  }

  for (int t = tb; t < te; ++t) {
    const float lx = px[last], ly = py[last], lz = pz[last];  // LDS broadcast
    float bv = -1.f;
    int bj = 0;
    #pragma unroll
    for (int j = 0; j < 16; ++j) {
      const float d = d2_exact(qx[j], qy[j], qz[j], lx, ly, lz);
      md[j] = fminf(md[j], d);
      if (md[j] > bv) { bv = md[j]; bj = j; }  // strict > : lowest j among ties
    }
    // key = (valbits<<32) | ~idx : u64 max == (max val, lowest idx) == jnp.argmax
    unsigned klo = ~(unsigned)(bj * 256 + tid);
    unsigned khi = __float_as_uint(bv);
    // DPP wavefront max-reduce to lane 63 (round-7 proven).
#define FPS_DPP_STAGE(CTRL, RMASK)                                                            \
    {                                                                                          \
      unsigned slo = (unsigned)__builtin_amdgcn_update_dpp(0, (int)klo, CTRL, RMASK, 0xf, true); \
      unsigned shi = (unsigned)__builtin_amdgcn_update_dpp(0, (int)khi, CTRL, RMASK, 0xf, true); \
      if ((((u64)shi << 32) | slo) > (((u64)khi << 32) | klo)) { khi = shi; klo = slo; }       \
    }
    FPS_DPP_STAGE(0x111, 0xf)  // row_shr:1
    FPS_DPP_STAGE(0x112, 0xf)  // row_shr:2
    FPS_DPP_STAGE(0x114, 0xf)  // row_shr:4
    FPS_DPP_STAGE(0x118, 0xf)  // row_shr:8
    FPS_DPP_STAGE(0x142, 0xa)  // row_bcast:15
    FPS_DPP_STAGE(0x143, 0xc)  // row_bcast:31 -> lane63 = wave max
#undef FPS_DPP_STAGE
    u64* sl = slots + (t & 1) * 4;
    if ((tid & 63) == 63) sl[tid >> 6] = ((u64)khi << 32) | klo;
    __syncthreads();  // single barrier/step; LDS-only traffic (no vmcnt drain)
    u64 mm = sl[0];
    #pragma unroll
    for (int w = 1; w < 4; ++w) mm = sl[w] > mm ? sl[w] : mm;
    last = (int)(~(unsigned)(mm & 0xffffffffull));
    if (tid == 0) sel[t - cbase] = last;   // buffer selection in LDS
  }

  // flush fps_idx + pos_out for this chunk (coalesced, off the critical path)
  __syncthreads();
  for (int e = tid; e < CHS; e += 256) {
    const int t2 = cbase + e;
    if (t2 == 0) continue;  // written at init
    const int idx = sel[e];
    fps_idx[bid * SSS + t2] = idx;
    pos_out[((size_t)bid * SSS + t2) * 3 + 0] = px[idx];
    pos_out[((size_t)bid * SSS + t2) * 3 + 1] = py[idx];
    pos_out[((size_t)bid * SSS + t2) * 3 + 2] = pz[idx];
  }
  if (chunk == 0) {
    #pragma unroll
    for (int j = 0; j < 16; ++j) md_ws[bid * 4096 + j * 256 + tid] = md[j];
    if (tid == 0) last_ws[bid] = last;
  }
}

// ---------------- y1 role: y1 = bf16(x @ W1[0:64,:]), XCD-affine (round-16 proven) ----------------
__device__ __forceinline__ void y1_role(int j, int tid,
                                        const float* __restrict__ x,
                                        const float* __restrict__ W1,
                                        unsigned short* __restrict__ y1,
                                        char* smem) {
  float* sW = (float*)smem;             // [64][128] 32KB
  float* sx = (float*)(smem + 32768);   // [8][64] 2KB
  const int cloud = ((j >> 12) << 3) | (j & 7);
  const int local = (j >> 3) & 511;
  const int p0 = cloud * NN + local * 8;
  for (int e = tid; e < CINN * HIDD; e += 256) sW[e] = W1[e];
  for (int e = tid; e < 8 * CINN; e += 256) sx[e] = x[(size_t)p0 * CINN + e];
  __syncthreads();
  const int h = tid & 127;
  const int pg = (tid >> 7) * 4;
  float a0 = 0.f, a1 = 0.f, a2 = 0.f, a3 = 0.f;
  for (int c = 0; c < CINN; ++c) {
    const float w = sW[c * HIDD + h];
    a0 = fmaf(sx[(pg + 0) * CINN + c], w, a0);
    a1 = fmaf(sx[(pg + 1) * CINN + c], w, a1);
    a2 = fmaf(sx[(pg + 2) * CINN + c], w, a2);
    a3 = fmaf(sx[(pg + 3) * CINN + c], w, a3);
  }
  y1[(size_t)(p0 + pg + 0) * HIDD + h] = f2bf(a0);
  y1[(size_t)(p0 + pg + 1) * HIDD + h] = f2bf(a1);
  y1[(size_t)(p0 + pg + 2) * HIDD + h] = f2bf(a2);
  y1[(size_t)(p0 + pg + 3) * HIDD + h] = f2bf(a3);
}

// ---------------- bq role: 8 centers/block, unrolled global scan (round-14 proven) ----------------
__device__ __forceinline__ void bq_role(int cc, int i, int tid,
                                        const float* __restrict__ pos,
                                        const int* __restrict__ fps_idx,
                                        int* __restrict__ nbr,
                                        int* __restrict__ cnt,
                                        char* smem) {
  const int b = i >> 6;                        // 64 blocks per cloud per half (CHS=512)
  const int t0 = cc * CHS + (i & 63) * 8;
  const int gbase = b * SSS + t0;
  float* cd = (float*)smem;                    // [8][MAXC]
  int*   ci = (int*)(smem + 10240);            // [8][MAXC]
  int*   ctr = (int*)(smem + 20480);           // [8]
  int*   scn = ctr + 8;                        // [8]
  float* cctr = (float*)(scn + 8);             // [8][3]

  const float* pb = pos + (size_t)b * NN * 3;
  if (tid < 8) { ctr[tid] = 0; scn[tid] = 0; }
  if (tid < 8) {
    const int cp = fps_idx[gbase + tid];
    cctr[tid * 3 + 0] = pb[cp * 3 + 0];
    cctr[tid * 3 + 1] = pb[cp * 3 + 1];
    cctr[tid * 3 + 2] = pb[cp * 3 + 2];
  }
  __syncthreads();
  float cx[8], cy[8], cz[8];
  #pragma unroll
  for (int c = 0; c < 8; ++c) {
    cx[c] = cctr[c * 3 + 0]; cy[c] = cctr[c * 3 + 1]; cz[c] = cctr[c * 3 + 2];
  }
  #pragma unroll 4
  for (int s2 = 0; s2 < 16; ++s2) {
    const int p = s2 * 256 + tid;
    const float x = pb[3 * p + 0], y = pb[3 * p + 1], z = pb[3 * p + 2];
    #pragma unroll
    for (int c = 0; c < 8; ++c) {
      const float d2 = d2_exact(x, y, z, cx[c], cy[c], cz[c]);
      if (d2 <= 0.04f) {
        const int slot = atomicAdd(&ctr[c], 1);
        if (slot < MAXC) { cd[c * MAXC + slot] = d2; ci[c * MAXC + slot] = p; }
      }
    }
  }
  __syncthreads();
  // exact lex-rank (d2, idx) top-K == lax.top_k tie-break; order-independent
  #pragma unroll 1
  for (int c = 0; c < 8; ++c) {
    const int C = min(ctr[c], MAXC);
    for (int j = tid; j < C; j += 256) {
      const float dj = cd[c * MAXC + j];
      const int ij = ci[c * MAXC + j];
      int rank = 0;
      for (int m = 0; m < C; ++m) {
        const float dm = cd[c * MAXC + m];
        const int im = ci[c * MAXC + m];
        rank += (dm < dj || (dm == dj && im < ij)) ? 1 : 0;
      }
      if (rank < KKK) nbr[(size_t)(gbase + c) * KKK + atomicAdd(&scn[c], 1)] = ij;
    }
  }
  __syncthreads();
  if (tid < 8) cnt[gbase + tid] = scn[tid];
}

// ---------------- mlp role: ONE center per block (18.4KB LDS -> 8 blocks/CU, 2x TLP).
// Per-element arithmetic identical to round-19; only the max-over-k is split across two
// wave-halves and combined via LDS (fmax is order-independent -> bit-identical). ----------------
__device__ __forceinline__ void mlp1c_role(int cc, int m, int tid,
                                           const float* __restrict__ pos,
                                           const unsigned short* __restrict__ y1,
                                           const float* __restrict__ W1,
                                           const float* __restrict__ b1,
                                           const unsigned short* __restrict__ W2t,
                                           const float* __restrict__ b2,
                                           const int* __restrict__ fps_idx,
                                           const int* __restrict__ nbr,
                                           const int* __restrict__ cnt,
                                           float* __restrict__ out,
                                           char* smem) {
  // m in [0,8192): XCD-affine; 512 centers/cloud/chunk (4096 per 8-cloud group)
  const int b = ((m >> 12) << 3) | (m & 7);
  const int loc = (m >> 3) & 511;
  const int g = b * SSS + cc * CHS + loc;
  char* Hb = smem;                          // [64][256B] swizzled = 16KB
  float* s_ctr = (float*)(smem + 16384);    // [3]
  int* s_M     = (int*)(smem + 16396);      // [1]
  int* s_pidx  = (int*)(smem + 16400);      // [64]
  float* s_rel = (float*)(smem + 16656);    // [64][3]
  float* s_pm  = (float*)(smem + 17424);    // [2][2][64] partial col-maxes (1KB)

  const int wv = tid >> 6, ln = tid & 63;
  const int mh = wv >> 1, nw = wv & 1;
  const int lr = ln & 15, lg = ln >> 4;

  if (tid == 0) {
    s_M[0] = min(cnt[g], KKK);
    const int cp = fps_idx[g];
    s_ctr[0] = pos[((size_t)b * NN + cp) * 3 + 0];
    s_ctr[1] = pos[((size_t)b * NN + cp) * 3 + 1];
    s_ctr[2] = pos[((size_t)b * NN + cp) * 3 + 2];
  }
  __syncthreads();

  // cooperative precompute: neighbor index + rel for the 64 rows
  if (tid < 64) {
    int p = -1;
    float rx = 0.f, ry = 0.f, rz = 0.f;
    if (tid < s_M[0]) {
      p = nbr[(size_t)g * KKK + tid];
      rx = pos[((size_t)b * NN + p) * 3 + 0] - s_ctr[0];
      ry = pos[((size_t)b * NN + p) * 3 + 1] - s_ctr[1];
      rz = pos[((size_t)b * NN + p) * 3 + 2] - s_ctr[2];
    }
    s_pidx[tid] = p;
    s_rel[tid * 3 + 0] = rx; s_rel[tid * 3 + 1] = ry; s_rel[tid * 3 + 2] = rz;
  }
  __syncthreads();

  const float2 b1v = *(const float2*)(b1 + ln * 2);
  const float2 wav = *(const float2*)(W1 + 64 * HIDD + ln * 2);
  const float2 wbv = *(const float2*)(W1 + 65 * HIDD + ln * 2);
  const float2 wcv = *(const float2*)(W1 + 66 * HIDD + ln * 2);
  const int rbase = wv * 16;   // 16 rows per wave, 2 register batches of 8
  #pragma unroll
  for (int qb = 0; qb < 2; ++qb) {
    unsigned yreg[8];
    #pragma unroll
    for (int rr = 0; rr < 8; ++rr) {
      const int p = s_pidx[rbase + qb * 8 + rr];
      const int pa = p < 0 ? 0 : p;
      yreg[rr] = *(const unsigned*)(y1 + ((size_t)(b * NN + pa)) * HIDD + ln * 2);
    }
    #pragma unroll
    for (int rr = 0; rr < 8; ++rr) {
      const int r = rbase + qb * 8 + rr;
      const int p = s_pidx[r];
      unsigned val = 0u;
      if (p >= 0) {
        const float rx = s_rel[r * 3 + 0], ry = s_rel[r * 3 + 1], rz = s_rel[r * 3 + 2];
        const float y0 = __uint_as_float(yreg[rr] << 16);          // bf2f(low half)
        const float y1f = __uint_as_float(yreg[rr] & 0xffff0000u); // bf2f(high half)
        const float v0 = fmaxf(y0 + b1v.x + rx * wav.x + ry * wbv.x + rz * wcv.x, 0.f);
        const float v1 = fmaxf(y1f + b1v.y + rx * wav.y + ry * wbv.y + rz * wcv.y, 0.f);
        val = (unsigned)f2bf(v0) | ((unsigned)f2bf(v1) << 16);
      }
      *(unsigned*)(Hb + r * 256 + ((ln * 4) ^ ((r & 7) << 4))) = val;
    }
  }
  __syncthreads();

  // MFMA: wave (mh=row-half, nw=col-half); 2x4 16x16 tiles; K=128 in 4 steps of 32.
  f32x4 zero = {0.f, 0.f, 0.f, 0.f};
  f32x4 acc[2][4];
  #pragma unroll
  for (int mi = 0; mi < 2; ++mi)
    #pragma unroll
    for (int ni = 0; ni < 4; ++ni) acc[mi][ni] = zero;

  #pragma unroll
  for (int ks = 0; ks < 4; ++ks) {
    short8 bfr[4];
    #pragma unroll
    for (int ni = 0; ni < 4; ++ni)
      bfr[ni] = *(const short8*)(W2t + (size_t)(nw * 64 + ni * 16 + lr) * HIDD + ks * 32 + lg * 8);
    short8 af[2];
    #pragma unroll
    for (int mi = 0; mi < 2; ++mi) {
      const int row = mh * 32 + mi * 16 + lr;
      af[mi] = *(const short8*)(Hb + row * 256 + ((ks * 64 + lg * 16) ^ ((row & 7) << 4)));
    }
    #pragma unroll
    for (int mi = 0; mi < 2; ++mi)
      #pragma unroll
      for (int ni = 0; ni < 4; ++ni)
        acc[mi][ni] = __builtin_amdgcn_mfma_f32_16x16x32_bf16(af[mi], bfr[ni], acc[mi][ni], 0, 0, 0);
  }

  // epilogue: relu(acc+b2), mask k>=M, per-wave max over its 32 k's, cross-wave via LDS
  const int Mc = s_M[0];
  #pragma unroll
  for (int ni = 0; ni < 4; ++ni) {
    const float b2v = b2[nw * 64 + ni * 16 + lr];
    float cm = 0.f;
    #pragma unroll
    for (int mi = 0; mi < 2; ++mi)
      #pragma unroll
      for (int rr = 0; rr < 4; ++rr) {
        const int k = mh * 32 + mi * 16 + lg * 4 + rr;  // C layout: col=lane&15, row=(lane>>4)*4+reg
        const float v = fmaxf(acc[mi][ni][rr] + b2v, 0.f);
        cm = fmaxf(cm, k < Mc ? v : 0.f);
      }
    cm = fmaxf(cm, __shfl_xor(cm, 16, 64));
    cm = fmaxf(cm, __shfl_xor(cm, 32, 64));
    if (ln < 16) s_pm[(mh * 2 + nw) * 64 + ni * 16 + lr] = cm;
  }
  __syncthreads();
  if (mh == 0 && ln < 16) {
    #pragma unroll
    for (int ni = 0; ni < 4; ++ni) {
      const int c = nw * 64 + ni * 16 + lr;
      const float f = fmaxf(s_pm[(0 * 2 + nw) * 64 + ni * 16 + lr],
                            s_pm[(1 * 2 + nw) * 64 + ni * 16 + lr]);
      out[(size_t)g * HIDD + c] = f;
    }
  }
}

// ============ 4 launches: P0 FPSa||y1||W2t, P1 FPSb||bq0, P2 bq1||mlp0, P3 mlp1 ============
__global__ __launch_bounds__(256) void k_phase0(const float* __restrict__ x,
                                                const float* __restrict__ pos,
                                                const float* __restrict__ W1,
                                                const float* __restrict__ W2,
                                                unsigned short* __restrict__ W2t,
                                                int* __restrict__ fps_idx,
                                                unsigned short* __restrict__ y1,
                                                float* __restrict__ md_ws,
                                                int* __restrict__ last_ws,
                                                float* __restrict__ pos_out,
                                                float* __restrict__ batch_out) {
  __shared__ __align__(16) char smem[51264];
  const int bid = blockIdx.x, tid = threadIdx.x;
  if (bid < BB) {
    fps_role(0, bid, tid, pos, fps_idx, md_ws, last_ws, pos_out, batch_out, smem);
  } else if (bid < 16 + 8192) {
    y1_role(bid - 16, tid, x, W1, y1, smem);
  } else {
    for (int e = tid; e < HIDD * HIDD; e += 256) {
      const int n = e >> 7, hh = e & 127;
      W2t[e] = f2bf(W2[hh * HIDD + n]);   // W2t[n][h]
    }
  }
}

__global__ __launch_bounds__(256) void k_phase1(const float* __restrict__ pos,
                                                int* __restrict__ fps_idx,
                                                int* __restrict__ cnt,
                                                int* __restrict__ nbr,
                                                float* __restrict__ md_ws,
                                                int* __restrict__ last_ws,
                                                float* __restrict__ pos_out,
                                                float* __restrict__ batch_out) {
  __shared__ __align__(16) char smem[51264];
  const int bid = blockIdx.x, tid = threadIdx.x;
  if (bid < BB) {
    fps_role(1, bid, tid, pos, fps_idx, md_ws, last_ws, pos_out, batch_out, smem);
  } else {
    bq_role(0, bid - 16, tid, pos, fps_idx, nbr, cnt, smem);
  }
}

// P2: bq chunk 1 (1024 blocks) || mlp1c chunk 0 (8192 blocks)
__global__ __launch_bounds__(256) void k_phase2(const float* __restrict__ pos,
                                                const unsigned short* __restrict__ y1,
                                                const float* __restrict__ W1,
                                                const float* __restrict__ b1,
                                                const unsigned short* __restrict__ W2t,
                                                const float* __restrict__ b2,
                                                int* __restrict__ fps_idx,
                                                int* __restrict__ nbr,
                                                int* __restrict__ cnt,
                                                float* __restrict__ out) {
  __shared__ __align__(16) char smem[20736];
  const int bid = blockIdx.x, tid = threadIdx.x;
  if (bid < 1024) {
    bq_role(1, bid, tid, pos, fps_idx, nbr, cnt, smem);
  } else {
    mlp1c_role(0, bid - 1024, tid, pos, y1, W1, b1, W2t, b2, fps_idx, nbr, cnt, out, smem);
  }
}

__global__ __launch_bounds__(256) void k_phase3(const float* __restrict__ pos,
                                                const unsigned short* __restrict__ y1,
                                                const float* __restrict__ W1,
                                                const float* __restrict__ b1,
                                                const unsigned short* __restrict__ W2t,
                                                const float* __restrict__ b2,
                                                const int* __restrict__ fps_idx,
                                                const int* __restrict__ nbr,
                                                const int* __restrict__ cnt,
                                                float* __restrict__ out) {
  __shared__ __align__(16) char smem[18448];
  mlp1c_role(1, blockIdx.x, threadIdx.x, pos, y1, W1, b1, W2t, b2,
             fps_idx, nbr, cnt, out, smem);
}

extern "C" void kernel_launch(void* const* d_in, const int* in_sizes, int n_in,
                              void* d_out, int out_size, void* d_ws, size_t ws_size,
                              hipStream_t stream) {
  const float* x   = (const float*)d_in[0];
  const float* pos = (const float*)d_in[1];
  const float* W1  = (const float*)d_in[3];
  const float* b1  = (const float*)d_in[4];
  const float* W2  = (const float*)d_in[5];
  const float* b2  = (const float*)d_in[6];

  float* out       = (float*)d_out;                   // [B*S, HID]
  float* pos_out   = out + (size_t)BB * SSS * HIDD;   // [B*S, 3]
  float* batch_out = pos_out + (size_t)BB * SSS * 3;  // [B*S]

  int* fps_idx        = (int*)d_ws;                                          // 64 KB
  int* cnt            = (int*)((char*)d_ws + 65536);                         // 64 KB
  unsigned short* W2t = (unsigned short*)((char*)d_ws + 131072);             // 32 KB
  int* last_ws        = (int*)((char*)d_ws + 163840);                        // 64 B
  int* nbr            = (int*)((char*)d_ws + 262144);                        // 4 MB
  unsigned short* y1  = (unsigned short*)((char*)d_ws + 262144 + 4194304);   // 16 MB (bf16)
  float* md_ws        = (float*)((char*)d_ws + 262144 + 4194304 + 33554432); // 256 KB

  k_phase0<<<16 + 8192 + 1, 256, 0, stream>>>(x, pos, W1, W2, W2t, fps_idx, y1,
                                              md_ws, last_ws, pos_out, batch_out);
  k_phase1<<<16 + 1024, 256, 0, stream>>>(pos, fps_idx, cnt, nbr,
                                          md_ws, last_ws, pos_out, batch_out);
  k_phase2<<<1024 + 8192, 256, 0, stream>>>(pos, y1, W1, b1, W2t, b2,
                                            fps_idx, nbr, cnt, out);
  k_phase3<<<8192, 256, 0, stream>>>(pos, y1, W1, b1, W2t, b2,
                                     fps_idx, nbr, cnt, out);
}